// Round 2
// baseline (837.614 us; speedup 1.0000x reference)
//
#include <hip/hip_runtime.h>

// ShootingBlockMNModel1 — single persistent kernel.
// 20 GD steps on 12-dim Theta, each needing 36 data sums over K=1M samples;
// samples live in registers across all iterations; manual grid barrier per step.
//
// ws layout: double stats[21][40] @0 (zeroed each launch), unsigned ctr @6720.

#define LR 0.25f
#define NIT 20
#define SROW 40
#define NBLK 256
#define TPB 512
#define NTH (NBLK*TPB)
#define SLOTS 4   // pairs per thread; SLOTS*NTH*2 == 1048576 == K

__device__ __forceinline__ float fast_tanh(float x){
    float e = __expf(2.0f*x);          // x>>0: e=inf -> 1; x<<0: e=0 -> -1
    return 1.0f - 2.0f/(e+1.0f);
}

__device__ __forceinline__ double atomic_ld_f64(const double* p){
    unsigned long long v = __hip_atomic_load((const unsigned long long*)p,
                                             __ATOMIC_RELAXED, __HIP_MEMORY_SCOPE_AGENT);
    return __longlong_as_double(v);
}

__device__ __forceinline__ void accum_sample(float q0,float q1,float p0,float p1,
    float t1_00,float t1_01,float t1_10,float t1_11,
    float t2_00,float t2_01,float t2_10,float t2_11,float b2_0,float b2_1,
    float (&acc)[36]){
    float u0 = t2_00*q0 + t2_01*q1 + b2_0;
    float u1 = t2_10*q0 + t2_11*q1 + b2_1;
    float h0 = fast_tanh(u0), h1 = fast_tanh(u1);
    float s0 = 1.0f-h0*h0, s1 = 1.0f-h1*h1;
    float a0 = t1_00*p0 + t1_10*p1;      // (T1^T p)
    float a1 = t1_01*p0 + t1_11*p1;
    float w0 = a0*s0, w1 = a1*s1;
    float r0 = -2.0f*a0*h0*s0, r1 = -2.0f*a1*h1*s1;
    acc[0]+=p0*h0; acc[1]+=p0*h1; acc[2]+=p1*h0; acc[3]+=p1*h1;
    acc[4]+=p0;    acc[5]+=p1;
    acc[6]+=w0*q0; acc[7]+=w0*q1; acc[8]+=w1*q0; acc[9]+=w1*q1;
    acc[10]+=w0;   acc[11]+=w1;
    float ps00=p0*s0, ps01=p0*s1, ps10=p1*s0, ps11=p1*s1;
    acc[12]+=ps00*q0; acc[13]+=ps00*q1; acc[14]+=ps01*q0; acc[15]+=ps01*q1;
    acc[16]+=ps10*q0; acc[17]+=ps10*q1; acc[18]+=ps11*q0; acc[19]+=ps11*q1;
    acc[20]+=ps00; acc[21]+=ps01; acc[22]+=ps10; acc[23]+=ps11;
    float r0q0=r0*q0, r1q0=r1*q0;
    acc[24]+=r0q0*q0; acc[25]+=r0q0*q1; acc[26]+=r0*q1*q1;
    acc[27]+=r1q0*q0; acc[28]+=r1q0*q1; acc[29]+=r1*q1*q1;
    acc[30]+=r0q0; acc[31]+=r0*q1; acc[32]+=r1q0; acc[33]+=r1*q1;
    acc[34]+=r0; acc[35]+=r1;
}

__device__ __forceinline__ void compute_grad(const float* __restrict__ s,
                                             const float* __restrict__ th,
                                             const float* __restrict__ ksym,
                                             const float* __restrict__ ksymb,
                                             float c, float* g){
    const float Ivec[4]={1.f,0.f,0.f,1.f};
    #pragma unroll
    for(int j=0;j<4;j++){
        float kv=0.f;
        #pragma unroll
        for(int m=0;m<4;m++) kv += ksym[j*4+m]*th[m];
        g[j] = kv - c*s[j];
    }
    #pragma unroll
    for(int i2=0;i2<2;i2++)
        g[4+i2] = ksymb[i2*2+0]*th[4] + ksymb[i2*2+1]*th[5] - c*s[4+i2];
    #pragma unroll
    for(int j=0;j<4;j++){
        float kv=0.f;
        #pragma unroll
        for(int m=0;m<4;m++) kv += ksym[j*4+m]*(th[6+m]-Ivec[m]);
        g[6+j] = kv - c*s[6+j];
    }
    #pragma unroll
    for(int i2=0;i2<2;i2++)
        g[10+i2] = ksymb[i2*2+0]*th[10] + ksymb[i2*2+1]*th[11] - c*s[10+i2];
}

__global__ __launch_bounds__(TPB, 2) void k_fused(
    const float* __restrict__ inp, int K,
    const float* __restrict__ t1i, const float* __restrict__ b1i,
    const float* __restrict__ t2i, const float* __restrict__ b2i,
    const float* __restrict__ invK, const float* __restrict__ invKb,
    double* __restrict__ stats, unsigned* __restrict__ ctr,
    float* __restrict__ out)
{
    const int tid  = threadIdx.x;
    const int gtid = blockIdx.x*TPB + tid;
    const int pairs = K >> 1;
    const float c = 1.0f/(2.0f*(float)K);

    __shared__ float th[(NIT+1)*12];
    __shared__ float lm[(NIT+1)*12];
    __shared__ float ksym[16], ksymb[4];
    __shared__ float red[TPB/64][36];
    __shared__ float sdat[(NIT+1)*36];

    if(tid==0){
        th[0]=t1i[0]; th[1]=t1i[1]; th[2]=t1i[2]; th[3]=t1i[3];
        th[4]=b1i[0]; th[5]=b1i[1];
        th[6]=t2i[0]; th[7]=t2i[1]; th[8]=t2i[2]; th[9]=t2i[3];
        th[10]=b2i[0]; th[11]=b2i[1];
        for(int a=0;a<4;a++)
            for(int b=0;b<4;b++)
                ksym[a*4+b] = 0.5f*(invK[a*4+b]+invK[b*4+a]);
        for(int a=0;a<2;a++)
            for(int b=0;b<2;b++)
                ksymb[a*2+b] = 0.5f*(invKb[a*2+b]+invKb[b*2+a]);
    }

    // ---- load this thread's samples into registers (once) ----
    const float4* q4 = (const float4*)inp;
    const float4* p4 = (const float4*)(inp + 2*(size_t)K);
    float qa0[SLOTS],qa1[SLOTS],qb0[SLOTS],qb1[SLOTS];
    float pa0[SLOTS],pa1[SLOTS],pb0[SLOTS],pb1[SLOTS];
    int jv[SLOTS];
    #pragma unroll
    for(int s=0;s<SLOTS;s++){
        int j = gtid + s*NTH;
        jv[s] = (j<pairs) ? j : -1;
        int jc = (j<pairs) ? j : 0;
        float4 qq = q4[jc], pp = p4[jc];
        qa0[s]=qq.x; qa1[s]=qq.y; qb0[s]=qq.z; qb1[s]=qq.w;
        pa0[s]=pp.x; pa1[s]=pp.y; pb0[s]=pp.z; pb1[s]=pp.w;
        if(j>=pairs){ pa0[s]=0.f; pa1[s]=0.f; pb0[s]=0.f; pb1[s]=0.f; } // all stats ∝ p -> 0
    }

    // ---- forward: 21 stat reductions + 20 theta updates ----
    for(int k=0;k<=NIT;k++){
        __syncthreads();                      // th row k visible
        const float* T = th + k*12;
        const float t1_00=T[0], t1_01=T[1], t1_10=T[2], t1_11=T[3];
        const float t2_00=T[6], t2_01=T[7], t2_10=T[8], t2_11=T[9];
        const float b2_0=T[10], b2_1=T[11];

        float acc[36];
        #pragma unroll
        for(int j=0;j<36;j++) acc[j]=0.0f;
        #pragma unroll
        for(int s=0;s<SLOTS;s++){
            accum_sample(qa0[s],qa1[s],pa0[s],pa1[s],
                         t1_00,t1_01,t1_10,t1_11,t2_00,t2_01,t2_10,t2_11,b2_0,b2_1,acc);
            accum_sample(qb0[s],qb1[s],pb0[s],pb1[s],
                         t1_00,t1_01,t1_10,t1_11,t2_00,t2_01,t2_10,t2_11,b2_0,b2_1,acc);
        }

        const int lane = tid & 63, wave = tid >> 6;
        #pragma unroll
        for(int j=0;j<36;j++){
            float v = acc[j];
            v += __shfl_down(v,32); v += __shfl_down(v,16); v += __shfl_down(v,8);
            v += __shfl_down(v,4);  v += __shfl_down(v,2);  v += __shfl_down(v,1);
            if(lane==0) red[wave][j]=v;
        }
        __syncthreads();
        if(tid<36){
            double sum=0.0;
            #pragma unroll
            for(int w=0;w<TPB/64;w++) sum += (double)red[w][tid];
            __hip_atomic_fetch_add(&stats[k*SROW+tid], sum,
                                   __ATOMIC_RELAXED, __HIP_MEMORY_SCOPE_AGENT);
        }
        __syncthreads();                      // block's adds done before arrival
        if(tid==0){
            __threadfence();
            __hip_atomic_fetch_add(ctr, 1u, __ATOMIC_ACQ_REL, __HIP_MEMORY_SCOPE_AGENT);
            const unsigned goal = (unsigned)NBLK*(unsigned)(k+1);
            while(__hip_atomic_load(ctr, __ATOMIC_ACQUIRE, __HIP_MEMORY_SCOPE_AGENT) < goal)
                __builtin_amdgcn_s_sleep(1);
            __threadfence();
            if(k<NIT){
                float sg[12];
                #pragma unroll
                for(int j=0;j<12;j++) sg[j] = (float)atomic_ld_f64(&stats[k*SROW+j]);
                float g[12];
                compute_grad(sg, T, ksym, ksymb, c, g);
                #pragma unroll
                for(int j=0;j<12;j++) th[(k+1)*12+j] = T[j] - LR*g[j];
            }
        }
    }
    __syncthreads();

    // ---- cooperative load of all stats (coherent) -> LDS floats ----
    for(int j=tid; j<(NIT+1)*36; j+=TPB){
        int k = j/36, r = j - k*36;
        sdat[j] = (float)atomic_ld_f64(&stats[k*SROW+r]);
    }
    __syncthreads();

    // ---- backward 12-dim recursion (redundant per block) ----
    if(tid==0){
        float lv[12];
        compute_grad(sdat + 20*36, th + 20*12, ksym, ksymb, c, lv);
        #pragma unroll
        for(int j=0;j<12;j++) lm[20*12+j]=lv[j];
        for(int k=NIT-1;k>=0;k--){
            const float* s = sdat + k*36;
            float H[12];
            for(int a=0;a<2;a++)for(int b=0;b<2;b++){
                int j=a*2+b;
                float data = s[12+a*4+b*2+0]*lv[6+b*2+0]
                           + s[12+a*4+b*2+1]*lv[6+b*2+1]
                           + s[20+a*2+b]*lv[10+b];
                float kv=0.f;
                for(int m=0;m<4;m++) kv += ksym[j*4+m]*lv[m];
                H[j]=kv - c*data;
            }
            H[4] = ksymb[0]*lv[4] + ksymb[1]*lv[5];
            H[5] = ksymb[2]*lv[4] + ksymb[3]*lv[5];
            for(int cc=0;cc<2;cc++)for(int d=0;d<2;d++){
                int j=cc*2+d;
                float term1 = lv[0+cc]*s[12+0*4+cc*2+d] + lv[2+cc]*s[12+1*4+cc*2+d];
                float term2 = lv[6+cc*2+0]*s[24+cc*3+(0+d)] + lv[6+cc*2+1]*s[24+cc*3+(1+d)];
                float term3 = lv[10+cc]*s[30+cc*2+d];
                float kv=0.f;
                for(int m=0;m<4;m++) kv += ksym[j*4+m]*lv[6+m];
                H[6+j]=kv - c*(term1+term2+term3);
            }
            for(int cc=0;cc<2;cc++){
                float z1 = lv[0+cc]*s[20+0*2+cc] + lv[2+cc]*s[20+1*2+cc];
                float z2 = lv[6+cc*2+0]*s[30+cc*2+0] + lv[6+cc*2+1]*s[30+cc*2+1];
                float z3 = lv[10+cc]*s[34+cc];
                float kv = ksymb[cc*2+0]*lv[10] + ksymb[cc*2+1]*lv[11];
                H[10+cc]=kv - c*(z1+z2+z3);
            }
            #pragma unroll
            for(int j=0;j<12;j++) lv[j] -= LR*H[j];
            #pragma unroll
            for(int j=0;j<12;j++) lm[k*12+j]=lv[j];
        }
    }
    __syncthreads();

    // ---- final pass: dot_p B-sum over k, then outputs (q,p still in regs) ----
    float BA0[SLOTS],BA1[SLOTS],BB0[SLOTS],BB1[SLOTS];
    #pragma unroll
    for(int s=0;s<SLOTS;s++){ BA0[s]=0.f; BA1[s]=0.f; BB0[s]=0.f; BB1[s]=0.f; }

    for(int k=0;k<NIT;k++){
        const float* T = th + k*12;
        const float* L = lm + (k+1)*12;
        float t1_00=T[0],t1_01=T[1],t1_10=T[2],t1_11=T[3];
        float t2_00=T[6],t2_01=T[7],t2_10=T[8],t2_11=T[9],b2_0=T[10],b2_1=T[11];
        float L1_00=L[0],L1_01=L[1],L1_10=L[2],L1_11=L[3];
        float L2_00=L[6],L2_01=L[7],L2_10=L[8],L2_11=L[9],lb2_0=L[10],lb2_1=L[11];
        #pragma unroll
        for(int s=0;s<SLOTS;s++){
            #pragma unroll
            for(int half=0; half<2; half++){
                float q0 = half? qb0[s]:qa0[s], q1 = half? qb1[s]:qa1[s];
                float p0 = half? pb0[s]:pa0[s], p1 = half? pb1[s]:pa1[s];
                float u0=t2_00*q0+t2_01*q1+b2_0;
                float u1=t2_10*q0+t2_11*q1+b2_1;
                float h0=fast_tanh(u0), h1=fast_tanh(u1);
                float s0=1.f-h0*h0, s1=1.f-h1*h1;
                float a0=t1_00*p0+t1_10*p1;
                float a1=t1_01*p0+t1_11*p1;
                float w0=a0*s0, w1=a1*s1;
                float r0=-2.f*a0*h0*s0, r1=-2.f*a1*h1*s1;
                float lp0=L1_00*p0+L1_10*p1;
                float lp1=L1_01*p0+L1_11*p1;
                float z0=L2_00*q0+L2_01*q1+lb2_0;
                float z1=L2_10*q0+L2_11*q1+lb2_1;
                float m0=lp0*s0 + r0*z0;
                float m1=lp1*s1 + r1*z1;
                float db0 = t2_00*m0 + t2_10*m1 + L2_00*w0 + L2_10*w1;
                float db1 = t2_01*m0 + t2_11*m1 + L2_01*w0 + L2_11*w1;
                if(half){ BB0[s]+=db0; BB1[s]+=db1; } else { BA0[s]+=db0; BA1[s]+=db1; }
            }
        }
    }

    {   // epilogue at Theta_20
        const float* T = th + NIT*12;
        float t1_00=T[0],t1_01=T[1],t1_10=T[2],t1_11=T[3],b1_0=T[4],b1_1=T[5];
        float t2_00=T[6],t2_01=T[7],t2_10=T[8],t2_11=T[9],b2_0=T[10],b2_1=T[11];
        const float4* x4 = (const float4*)(inp + 4*(size_t)K);
        float4* oq = (float4*)out;
        float4* op = (float4*)(out + 2*(size_t)K);
        float4* ox = (float4*)(out + 4*(size_t)K);
        #pragma unroll
        for(int s=0;s<SLOTS;s++){
            int j = jv[s];
            if(j < 0) continue;
            float dq[4], dp[4];
            #pragma unroll
            for(int half=0; half<2; half++){
                float q0 = half? qb0[s]:qa0[s], q1 = half? qb1[s]:qa1[s];
                float p0 = half? pb0[s]:pa0[s], p1 = half? pb1[s]:pa1[s];
                float B0 = half? BB0[s]:BA0[s], B1 = half? BB1[s]:BA1[s];
                float u0=t2_00*q0+t2_01*q1+b2_0;
                float u1=t2_10*q0+t2_11*q1+b2_1;
                float h0=fast_tanh(u0), h1=fast_tanh(u1);
                float s0=1.f-h0*h0, s1=1.f-h1*h1;
                float a0=t1_00*p0+t1_10*p1;
                float a1=t1_01*p0+t1_11*p1;
                float w0=a0*s0, w1=a1*s1;
                dq[half*2+0] = t1_00*h0 + t1_01*h1 + b1_0;
                dq[half*2+1] = t1_10*h0 + t1_11*h1 + b1_1;
                float dir0 = t2_00*w0 + t2_10*w1;
                float dir1 = t2_01*w0 + t2_11*w1;
                dp[half*2+0] = c*(LR*B0 - dir0);
                dp[half*2+1] = c*(LR*B1 - dir1);
            }
            oq[j] = make_float4(dq[0],dq[1],dq[2],dq[3]);
            op[j] = make_float4(dp[0],dp[1],dp[2],dp[3]);
            float4 xx = x4[j];
            float xu0=t2_00*xx.x+t2_01*xx.y+b2_0;
            float xu1=t2_10*xx.x+t2_11*xx.y+b2_1;
            float xv0=t2_00*xx.z+t2_01*xx.w+b2_0;
            float xv1=t2_10*xx.z+t2_11*xx.w+b2_1;
            float xh0=fast_tanh(xu0), xh1=fast_tanh(xu1);
            float xh2=fast_tanh(xv0), xh3=fast_tanh(xv1);
            ox[j] = make_float4(t1_00*xh0 + t1_01*xh1 + b1_0,
                                t1_10*xh0 + t1_11*xh1 + b1_1,
                                t1_00*xh2 + t1_01*xh3 + b1_0,
                                t1_10*xh2 + t1_11*xh3 + b1_1);
        }
    }
}

extern "C" void kernel_launch(void* const* d_in, const int* in_sizes, int n_in,
                              void* d_out, int out_size, void* d_ws, size_t ws_size,
                              hipStream_t stream) {
    const float* inp = (const float*)d_in[1];
    const int K = in_sizes[1]/6;

    double* stats = (double*)d_ws;                           // [21][40]
    unsigned* ctr = (unsigned*)((char*)d_ws + 21*SROW*sizeof(double));

    hipMemsetAsync(d_ws, 0, 21*SROW*sizeof(double) + 64, stream);
    k_fused<<<NBLK, TPB, 0, stream>>>(inp, K,
                                      (const float*)d_in[2], (const float*)d_in[3],
                                      (const float*)d_in[4], (const float*)d_in[5],
                                      (const float*)d_in[6], (const float*)d_in[7],
                                      stats, ctr, (float*)d_out);
}

// Round 3
// 537.614 us; speedup vs baseline: 1.5580x; 1.5580x over previous
//
#include <hip/hip_runtime.h>

// ShootingBlockMNModel1 — multi-kernel, self-updating reduction passes.
// Pass k: every block recomputes theta_k from stats_{k-1} (cross-dispatch
// visibility via kernel boundary), then accumulates 36 data sums over K samples.
// No grid barrier, no k_update launches.
//
// ws layout:
//   double stats[21][40] @ 0      (zeroed via hipMemsetAsync)
//   float  theta[21][12] @ 6720
//   float  lam[21][12]   @ 7728   (offsets kept 16B-aligned)
//   float  ksym[16]      @ 8736
//   float  ksymb[4]      @ 8800

#define LR 0.25f
#define NIT 20
#define SROW 40
#define RBLK 256
#define RTPB 1024
#define RTH (RBLK*RTPB)

__device__ __forceinline__ float fast_tanh(float x){
    float e = __expf(2.0f*x);
    return 1.0f - 2.0f/(e+1.0f);
}

__device__ __forceinline__ void compute_grad(const float* __restrict__ s,
                                             const float* __restrict__ th,
                                             const float* __restrict__ ksym,
                                             const float* __restrict__ ksymb,
                                             float c, float* g){
    const float Ivec[4]={1.f,0.f,0.f,1.f};
    #pragma unroll
    for(int j=0;j<4;j++){
        float kv=0.f;
        #pragma unroll
        for(int m=0;m<4;m++) kv += ksym[j*4+m]*th[m];
        g[j] = kv - c*s[j];
    }
    #pragma unroll
    for(int i2=0;i2<2;i2++)
        g[4+i2] = ksymb[i2*2+0]*th[4] + ksymb[i2*2+1]*th[5] - c*s[4+i2];
    #pragma unroll
    for(int j=0;j<4;j++){
        float kv=0.f;
        #pragma unroll
        for(int m=0;m<4;m++) kv += ksym[j*4+m]*(th[6+m]-Ivec[m]);
        g[6+j] = kv - c*s[6+j];
    }
    #pragma unroll
    for(int i2=0;i2<2;i2++)
        g[10+i2] = ksymb[i2*2+0]*th[10] + ksymb[i2*2+1]*th[11] - c*s[10+i2];
}

__global__ void k_setup(const float* __restrict__ t1i, const float* __restrict__ b1i,
                        const float* __restrict__ t2i, const float* __restrict__ b2i,
                        const float* __restrict__ invK, const float* __restrict__ invKb,
                        float* __restrict__ theta, float* __restrict__ ksym,
                        float* __restrict__ ksymb){
    if(threadIdx.x==0 && blockIdx.x==0){
        theta[0]=t1i[0]; theta[1]=t1i[1]; theta[2]=t1i[2]; theta[3]=t1i[3];
        theta[4]=b1i[0]; theta[5]=b1i[1];
        theta[6]=t2i[0]; theta[7]=t2i[1]; theta[8]=t2i[2]; theta[9]=t2i[3];
        theta[10]=b2i[0]; theta[11]=b2i[1];
        for(int a=0;a<4;a++)
            for(int b=0;b<4;b++)
                ksym[a*4+b] = 0.5f*(invK[a*4+b]+invK[b*4+a]);
        for(int a=0;a<2;a++)
            for(int b=0;b<2;b++)
                ksymb[a*2+b] = 0.5f*(invKb[a*2+b]+invKb[b*2+a]);
    }
}

__device__ __forceinline__ void accum_sample(float q0,float q1,float p0,float p1,
    float t1_00,float t1_01,float t1_10,float t1_11,
    float t2_00,float t2_01,float t2_10,float t2_11,float b2_0,float b2_1,
    float (&acc)[36]){
    float u0 = t2_00*q0 + t2_01*q1 + b2_0;
    float u1 = t2_10*q0 + t2_11*q1 + b2_1;
    float h0 = fast_tanh(u0), h1 = fast_tanh(u1);
    float s0 = 1.0f-h0*h0, s1 = 1.0f-h1*h1;
    float a0 = t1_00*p0 + t1_10*p1;      // (T1^T p)
    float a1 = t1_01*p0 + t1_11*p1;
    float w0 = a0*s0, w1 = a1*s1;
    float r0 = -2.0f*a0*h0*s0, r1 = -2.0f*a1*h1*s1;
    acc[0]+=p0*h0; acc[1]+=p0*h1; acc[2]+=p1*h0; acc[3]+=p1*h1;
    acc[4]+=p0;    acc[5]+=p1;
    acc[6]+=w0*q0; acc[7]+=w0*q1; acc[8]+=w1*q0; acc[9]+=w1*q1;
    acc[10]+=w0;   acc[11]+=w1;
    float ps00=p0*s0, ps01=p0*s1, ps10=p1*s0, ps11=p1*s1;
    acc[12]+=ps00*q0; acc[13]+=ps00*q1; acc[14]+=ps01*q0; acc[15]+=ps01*q1;
    acc[16]+=ps10*q0; acc[17]+=ps10*q1; acc[18]+=ps11*q0; acc[19]+=ps11*q1;
    acc[20]+=ps00; acc[21]+=ps01; acc[22]+=ps10; acc[23]+=ps11;
    float r0q0=r0*q0, r1q0=r1*q0;
    acc[24]+=r0q0*q0; acc[25]+=r0q0*q1; acc[26]+=r0*q1*q1;
    acc[27]+=r1q0*q0; acc[28]+=r1q0*q1; acc[29]+=r1*q1*q1;
    acc[30]+=r0q0; acc[31]+=r0*q1; acc[32]+=r1q0; acc[33]+=r1*q1;
    acc[34]+=r0; acc[35]+=r1;
}

// One pass: recompute theta_k from stats_{k-1} (redundant per block), then
// accumulate 36 sums over all samples at theta_k.
__global__ __launch_bounds__(RTPB, 4) void k_reduce(
    const float4* __restrict__ q4, const float4* __restrict__ p4, int pairs,
    const float* __restrict__ theta_prev,   // row k-1 (row 0 when k==0)
    const double* __restrict__ stats_prev,  // row k-1, or nullptr when k==0
    double* __restrict__ stats,             // row k (accumulate into)
    float* __restrict__ theta_out,          // row k (block 0 persists)
    const float* __restrict__ ksym_g, const float* __restrict__ ksymb_g,
    float c)
{
    const int tid = threadIdx.x;
    __shared__ float ths[12];
    __shared__ float red[RTPB/64][36];

    // issue data loads first so they overlap the theta recompute
    const int gtid = blockIdx.x*RTPB + tid;
    float4 qq[2], pp[2];
    #pragma unroll
    for(int s=0;s<2;s++){
        int j = gtid + s*RTH;
        bool ok = (j<pairs);
        int jc = ok ? j : 0;
        qq[s]=q4[jc]; pp[s]=p4[jc];
        if(!ok){ pp[s].x=0.f; pp[s].y=0.f; pp[s].z=0.f; pp[s].w=0.f; } // stats ∝ p
    }

    if(tid==0){
        float tcur[12];
        if(stats_prev){
            float sg[12];
            #pragma unroll
            for(int j=0;j<12;j++) sg[j]=(float)stats_prev[j];
            float g[12];
            compute_grad(sg, theta_prev, ksym_g, ksymb_g, c, g);
            #pragma unroll
            for(int j=0;j<12;j++) tcur[j] = theta_prev[j] - LR*g[j];
            if(blockIdx.x==0){
                #pragma unroll
                for(int j=0;j<12;j++) theta_out[j]=tcur[j];
            }
        }else{
            #pragma unroll
            for(int j=0;j<12;j++) tcur[j] = theta_prev[j];
        }
        #pragma unroll
        for(int j=0;j<12;j++) ths[j]=tcur[j];
    }
    __syncthreads();

    const float t1_00=ths[0], t1_01=ths[1], t1_10=ths[2], t1_11=ths[3];
    const float t2_00=ths[6], t2_01=ths[7], t2_10=ths[8], t2_11=ths[9];
    const float b2_0=ths[10], b2_1=ths[11];

    float acc[36];
    #pragma unroll
    for(int j=0;j<36;j++) acc[j]=0.0f;
    #pragma unroll
    for(int s=0;s<2;s++){
        accum_sample(qq[s].x,qq[s].y,pp[s].x,pp[s].y,
                     t1_00,t1_01,t1_10,t1_11,t2_00,t2_01,t2_10,t2_11,b2_0,b2_1,acc);
        accum_sample(qq[s].z,qq[s].w,pp[s].z,pp[s].w,
                     t1_00,t1_01,t1_10,t1_11,t2_00,t2_01,t2_10,t2_11,b2_0,b2_1,acc);
    }

    const int lane = tid & 63, wave = tid >> 6;
    #pragma unroll
    for(int j=0;j<36;j++){
        float v = acc[j];
        v += __shfl_down(v,32); v += __shfl_down(v,16); v += __shfl_down(v,8);
        v += __shfl_down(v,4);  v += __shfl_down(v,2);  v += __shfl_down(v,1);
        if(lane==0) red[wave][j]=v;
    }
    __syncthreads();
    if(tid<36){
        double sum=0.0;
        #pragma unroll
        for(int w=0;w<RTPB/64;w++) sum += (double)red[w][tid];
        __hip_atomic_fetch_add(&stats[tid], sum,
                               __ATOMIC_RELAXED, __HIP_MEMORY_SCOPE_AGENT);
    }
}

// lambda_20 = g(Theta_20); lambda_k = lambda_{k+1} - LR * H_k lambda_{k+1}
__global__ void k_backward(const double* __restrict__ statsAll,
                           const float* __restrict__ thetaAll,
                           float* __restrict__ lamAll,
                           const float* __restrict__ ksym,
                           const float* __restrict__ ksymb, float c){
    if(threadIdx.x!=0 || blockIdx.x!=0) return;
    float sg[12];
    for(int j=0;j<12;j++) sg[j]=(float)statsAll[20*SROW+j];
    float lv[12];
    compute_grad(sg, thetaAll + 20*12, ksym, ksymb, c, lv);
    for(int j=0;j<12;j++) lamAll[20*12+j]=lv[j];
    for(int k=NIT-1;k>=0;k--){
        const double* sd = statsAll + k*SROW;
        float s[36];
        for(int j=0;j<36;j++) s[j]=(float)sd[j];
        float H[12];
        for(int a=0;a<2;a++)for(int b=0;b<2;b++){
            int j=a*2+b;
            float data = s[12+a*4+b*2+0]*lv[6+b*2+0]
                       + s[12+a*4+b*2+1]*lv[6+b*2+1]
                       + s[20+a*2+b]*lv[10+b];
            float kv=0.f;
            for(int m=0;m<4;m++) kv += ksym[j*4+m]*lv[m];
            H[j]=kv - c*data;
        }
        H[4] = ksymb[0]*lv[4] + ksymb[1]*lv[5];
        H[5] = ksymb[2]*lv[4] + ksymb[3]*lv[5];
        for(int cc=0;cc<2;cc++)for(int d=0;d<2;d++){
            int j=cc*2+d;
            float term1 = lv[0+cc]*s[12+0*4+cc*2+d] + lv[2+cc]*s[12+1*4+cc*2+d];
            float term2 = lv[6+cc*2+0]*s[24+cc*3+(0+d)] + lv[6+cc*2+1]*s[24+cc*3+(1+d)];
            float term3 = lv[10+cc]*s[30+cc*2+d];
            float kv=0.f;
            for(int m=0;m<4;m++) kv += ksym[j*4+m]*lv[6+m];
            H[6+j]=kv - c*(term1+term2+term3);
        }
        for(int cc=0;cc<2;cc++){
            float z1 = lv[0+cc]*s[20+0*2+cc] + lv[2+cc]*s[20+1*2+cc];
            float z2 = lv[6+cc*2+0]*s[30+cc*2+0] + lv[6+cc*2+1]*s[30+cc*2+1];
            float z3 = lv[10+cc]*s[34+cc];
            float kv = ksymb[cc*2+0]*lv[10] + ksymb[cc*2+1]*lv[11];
            H[10+cc]=kv - c*(z1+z2+z3);
        }
        for(int j=0;j<12;j++) lv[j] -= LR*H[j];
        for(int j=0;j<12;j++) lamAll[k*12+j]=lv[j];
    }
}

__device__ __forceinline__ void bk_step(float q0,float q1,float p0,float p1,
    float t1_00,float t1_01,float t1_10,float t1_11,
    float t2_00,float t2_01,float t2_10,float t2_11,float b2_0,float b2_1,
    float L1_00,float L1_01,float L1_10,float L1_11,
    float L2_00,float L2_01,float L2_10,float L2_11,float lb2_0,float lb2_1,
    float &B0, float &B1){
    float u0=t2_00*q0+t2_01*q1+b2_0;
    float u1=t2_10*q0+t2_11*q1+b2_1;
    float h0=fast_tanh(u0), h1=fast_tanh(u1);
    float s0=1.f-h0*h0, s1=1.f-h1*h1;
    float a0=t1_00*p0+t1_10*p1;
    float a1=t1_01*p0+t1_11*p1;
    float w0=a0*s0, w1=a1*s1;
    float r0=-2.f*a0*h0*s0, r1=-2.f*a1*h1*s1;
    float lp0=L1_00*p0+L1_10*p1;
    float lp1=L1_01*p0+L1_11*p1;
    float z0=L2_00*q0+L2_01*q1+lb2_0;
    float z1=L2_10*q0+L2_11*q1+lb2_1;
    float m0=lp0*s0 + r0*z0;
    float m1=lp1*s1 + r1*z1;
    B0 += t2_00*m0 + t2_10*m1 + L2_00*w0 + L2_10*w1;
    B1 += t2_01*m0 + t2_11*m1 + L2_01*w0 + L2_11*w1;
}

__global__ __launch_bounds__(256) void k_final(
    const float4* __restrict__ q4, const float4* __restrict__ p4,
    const float4* __restrict__ x4, int pairs,
    const float4* __restrict__ thetaAll4, const float4* __restrict__ lamAll4,
    float4* __restrict__ oq, float4* __restrict__ op, float4* __restrict__ ox,
    float c)
{
    __shared__ float4 th4[(NIT+1)*3];
    __shared__ float4 lm4[(NIT+1)*3];
    for(int j=threadIdx.x;j<(NIT+1)*3;j+=blockDim.x){ th4[j]=thetaAll4[j]; lm4[j]=lamAll4[j]; }
    __syncthreads();

    int j = blockIdx.x*blockDim.x + threadIdx.x;
    if(j>=pairs) return;
    float4 qq=q4[j], pp=p4[j];

    float BA0=0.f,BA1=0.f,BB0=0.f,BB1=0.f;
    #pragma unroll
    for(int k=0;k<NIT;k++){
        float4 Ta=th4[k*3+0], Tb=th4[k*3+1], Tc=th4[k*3+2];
        float4 La=lm4[(k+1)*3+0], Lb=lm4[(k+1)*3+1], Lc=lm4[(k+1)*3+2];
        float t1_00=Ta.x,t1_01=Ta.y,t1_10=Ta.z,t1_11=Ta.w;
        float t2_00=Tb.z,t2_01=Tb.w,t2_10=Tc.x,t2_11=Tc.y,b2_0=Tc.z,b2_1=Tc.w;
        float L1_00=La.x,L1_01=La.y,L1_10=La.z,L1_11=La.w;
        float L2_00=Lb.z,L2_01=Lb.w,L2_10=Lc.x,L2_11=Lc.y,lb2_0=Lc.z,lb2_1=Lc.w;
        bk_step(qq.x,qq.y,pp.x,pp.y,
                t1_00,t1_01,t1_10,t1_11,t2_00,t2_01,t2_10,t2_11,b2_0,b2_1,
                L1_00,L1_01,L1_10,L1_11,L2_00,L2_01,L2_10,L2_11,lb2_0,lb2_1,BA0,BA1);
        bk_step(qq.z,qq.w,pp.z,pp.w,
                t1_00,t1_01,t1_10,t1_11,t2_00,t2_01,t2_10,t2_11,b2_0,b2_1,
                L1_00,L1_01,L1_10,L1_11,L2_00,L2_01,L2_10,L2_11,lb2_0,lb2_1,BB0,BB1);
    }

    // epilogue at Theta_20
    float4 Ta=th4[NIT*3+0], Tb=th4[NIT*3+1], Tc=th4[NIT*3+2];
    float t1_00=Ta.x,t1_01=Ta.y,t1_10=Ta.z,t1_11=Ta.w,b1_0=Tb.x,b1_1=Tb.y;
    float t2_00=Tb.z,t2_01=Tb.w,t2_10=Tc.x,t2_11=Tc.y,b2_0=Tc.z,b2_1=Tc.w;

    float dq[4], dp[4];
    {
        float u0=t2_00*qq.x+t2_01*qq.y+b2_0;
        float u1=t2_10*qq.x+t2_11*qq.y+b2_1;
        float h0=fast_tanh(u0), h1=fast_tanh(u1);
        float s0=1.f-h0*h0, s1=1.f-h1*h1;
        float a0=t1_00*pp.x+t1_10*pp.y;
        float a1=t1_01*pp.x+t1_11*pp.y;
        float w0=a0*s0, w1=a1*s1;
        dq[0]=t1_00*h0 + t1_01*h1 + b1_0;
        dq[1]=t1_10*h0 + t1_11*h1 + b1_1;
        dp[0]=c*(LR*BA0 - (t2_00*w0 + t2_10*w1));
        dp[1]=c*(LR*BA1 - (t2_01*w0 + t2_11*w1));
    }
    {
        float u0=t2_00*qq.z+t2_01*qq.w+b2_0;
        float u1=t2_10*qq.z+t2_11*qq.w+b2_1;
        float h0=fast_tanh(u0), h1=fast_tanh(u1);
        float s0=1.f-h0*h0, s1=1.f-h1*h1;
        float a0=t1_00*pp.z+t1_10*pp.w;
        float a1=t1_01*pp.z+t1_11*pp.w;
        float w0=a0*s0, w1=a1*s1;
        dq[2]=t1_00*h0 + t1_01*h1 + b1_0;
        dq[3]=t1_10*h0 + t1_11*h1 + b1_1;
        dp[2]=c*(LR*BB0 - (t2_00*w0 + t2_10*w1));
        dp[3]=c*(LR*BB1 - (t2_01*w0 + t2_11*w1));
    }
    oq[j] = make_float4(dq[0],dq[1],dq[2],dq[3]);
    op[j] = make_float4(dp[0],dp[1],dp[2],dp[3]);
    float4 xx = x4[j];
    float xu0=t2_00*xx.x+t2_01*xx.y+b2_0;
    float xu1=t2_10*xx.x+t2_11*xx.y+b2_1;
    float xv0=t2_00*xx.z+t2_01*xx.w+b2_0;
    float xv1=t2_10*xx.z+t2_11*xx.w+b2_1;
    float xh0=fast_tanh(xu0), xh1=fast_tanh(xu1);
    float xh2=fast_tanh(xv0), xh3=fast_tanh(xv1);
    ox[j] = make_float4(t1_00*xh0 + t1_01*xh1 + b1_0,
                        t1_10*xh0 + t1_11*xh1 + b1_1,
                        t1_00*xh2 + t1_01*xh3 + b1_0,
                        t1_10*xh2 + t1_11*xh3 + b1_1);
}

extern "C" void kernel_launch(void* const* d_in, const int* in_sizes, int n_in,
                              void* d_out, int out_size, void* d_ws, size_t ws_size,
                              hipStream_t stream) {
    const float* inp = (const float*)d_in[1];
    const int K = in_sizes[1]/6;
    const int pairs = K >> 1;

    const float4* q4 = (const float4*)inp;
    const float4* p4 = (const float4*)(inp + 2*(size_t)K);
    const float4* x4 = (const float4*)(inp + 4*(size_t)K);

    double* stats = (double*)d_ws;                                  // [21][40]
    float* theta  = (float*)((char*)d_ws + 6720);                   // [21][12]
    float* lam    = (float*)((char*)d_ws + 7728);                   // [21][12]
    float* ksym   = (float*)((char*)d_ws + 8736);                   // [16]
    float* ksymb  = (float*)((char*)d_ws + 8800);                   // [4]
    const float c = 1.0f/(2.0f*(float)K);

    hipMemsetAsync(stats, 0, 21*SROW*sizeof(double), stream);
    k_setup<<<1,64,0,stream>>>((const float*)d_in[2],(const float*)d_in[3],
                               (const float*)d_in[4],(const float*)d_in[5],
                               (const float*)d_in[6],(const float*)d_in[7],
                               theta, ksym, ksymb);

    for(int k=0;k<=NIT;k++){
        const float* th_prev = (k==0) ? theta : theta + (k-1)*12;
        const double* st_prev = (k==0) ? nullptr : stats + (k-1)*SROW;
        k_reduce<<<RBLK,RTPB,0,stream>>>(q4, p4, pairs,
                                         th_prev, st_prev,
                                         stats + k*SROW, theta + k*12,
                                         ksym, ksymb, c);
    }
    k_backward<<<1,64,0,stream>>>(stats, theta, lam, ksym, ksymb, c);

    float* out = (float*)d_out;
    int fblk = (pairs + 255)/256;
    k_final<<<fblk,256,0,stream>>>(q4, p4, x4, pairs,
                                   (const float4*)theta, (const float4*)lam,
                                   (float4*)out, (float4*)(out + 2*(size_t)K),
                                   (float4*)(out + 4*(size_t)K), c);
}